// Round 6
// baseline (773.659 us; speedup 1.0000x reference)
//
#include <hip/hip_runtime.h>
#include <hip/hip_bf16.h>
#include <stdint.h>

#define N_NODES 500000
#define F 128
#define B 20000
#define T 8
#define H1 128
#define H2 64
#define C 32
#define S1 5
#define S2 2
#define BK 8

// async 16B global -> LDS (direct-to-shared DMA, no VGPR round trip).
// LDS dest is wave-uniform base + lane*16; global src is per-lane.
__device__ __forceinline__ void async_cp16(const float* g, float* l) {
    __builtin_amdgcn_global_load_lds(
        (const __attribute__((address_space(1))) uint32_t*)g,
        (__attribute__((address_space(3))) uint32_t*)l,
        16, 0, 0);
}

// ---------------------------------------------------------------------------
// K1: PQ[n] = [ x[n]@w_l0 + b_l0 | x[n]@w_r0 + b_r0 ]   (500000 x 256 fp32)
// Each block computes ONE half (P or Q): BM=64 rows x BN=128 cols, BK=8,
// 256 threads, 8x4 outputs/thread (acc = 32 VGPRs). Double-buffered LDS
// (12.25 KB) staged via global_load_lds. Small footprint -> ~6 blocks/CU
// resident (R2/R5 lesson: 41KB LDS pinned occupancy at 22% and the VALU
// idled at barriers; R3/R4 lesson: register prefetch spills acc).
// ---------------------------------------------------------------------------
__global__ __launch_bounds__(256) void k1_pq(
    const float* __restrict__ x,
    const float* __restrict__ w_l0, const float* __restrict__ b_l0,
    const float* __restrict__ w_r0, const float* __restrict__ b_r0,
    float* __restrict__ PQ)
{
    __shared__ float Ar[2][64][BK];     // [buf][row][k]   2 KB each
    __shared__ float Wt[2][BK][128];    // [buf][k][col]   4 KB each

    const int tid  = threadIdx.x;
    const int tx   = tid & 31;          // col group: cols tx*4..tx*4+3
    const int ty   = tid >> 5;          // row group: rows ty*8..ty*8+7
    const int wv   = tid >> 6;          // wave id 0..3
    const int lane = tid & 63;
    const int bid  = blockIdx.x;
    const int half = bid & 1;           // 0 = P (w_l0), 1 = Q (w_r0)
    const int m0   = (bid >> 1) * 64;

    const float* wmat = half ? w_r0 : w_l0;
    const float* bvec = half ? b_r0 : b_l0;

    float acc[8][4];
    #pragma unroll
    for (int i = 0; i < 8; i++)
        #pragma unroll
        for (int j = 0; j < 4; j++) acc[i][j] = 0.f;

    if (m0 + 64 <= N_NODES) {
        // ---------- full block: async double-buffered pipeline ------------
        // A staging (waves 0,1): wave w covers rows w*32..w*32+31
        const float* ag = x + (size_t)(m0 + (wv & 1) * 32 + (lane >> 1)) * F
                            + (lane & 1) * 4;
        // W staging (all 4 waves): wave w covers k rows w*2, w*2+1
        const float* wg = wmat + (size_t)(wv * 2 + (lane >> 5)) * F
                               + (lane & 31) * 4;

        // prologue: stage tile 0 into buf 0
        if (wv < 2) async_cp16(ag, &Ar[0][wv * 32][0]);
        async_cp16(wg, &Wt[0][wv * 2][0]);
        __syncthreads();

        for (int it = 0; it < F / BK; ++it) {
            const int cur = it & 1;
            if (it < F / BK - 1) {      // issue next tile early (async)
                const int kk1 = (it + 1) * BK;
                if (wv < 2) async_cp16(ag + kk1, &Ar[cur ^ 1][wv * 32][0]);
                async_cp16(wg + (size_t)kk1 * F, &Wt[cur ^ 1][wv * 2][0]);
            }
            #pragma unroll
            for (int k2 = 0; k2 < BK / 2; ++k2) {
                float2 a2[8];
                #pragma unroll
                for (int r = 0; r < 8; ++r)
                    a2[r] = *(const float2*)&Ar[cur][ty * 8 + r][k2 * 2];
                #pragma unroll
                for (int kk2 = 0; kk2 < 2; ++kk2) {
                    float4 w = *(const float4*)&Wt[cur][k2 * 2 + kk2][tx * 4];
                    #pragma unroll
                    for (int r = 0; r < 8; ++r) {
                        float av = kk2 ? a2[r].y : a2[r].x;
                        acc[r][0] += av * w.x;
                        acc[r][1] += av * w.y;
                        acc[r][2] += av * w.z;
                        acc[r][3] += av * w.w;
                    }
                }
            }
            __syncthreads();            // drains async loads + orders buffers
        }
    } else {
        // ---------- tail block (rows 499968..499999): checked path --------
        const int arow = m0 + (tid >> 2);
        for (int it = 0; it < F / BK; ++it) {
            const int kk = it * BK;
            float2 av = make_float2(0.f, 0.f);
            if (arow < N_NODES)
                av = *(const float2*)(x + (size_t)arow * F + kk + (tid & 3) * 2);
            *(float2*)&Ar[0][tid >> 2][(tid & 3) * 2] = av;
            float4 wv4 = *(const float4*)(wmat + (size_t)(kk + (tid >> 5)) * F
                                               + (tid & 31) * 4);
            *(float4*)&Wt[0][tid >> 5][(tid & 31) * 4] = wv4;
            __syncthreads();
            #pragma unroll
            for (int k2 = 0; k2 < BK / 2; ++k2) {
                float2 a2[8];
                #pragma unroll
                for (int r = 0; r < 8; ++r)
                    a2[r] = *(const float2*)&Ar[0][ty * 8 + r][k2 * 2];
                #pragma unroll
                for (int kk2 = 0; kk2 < 2; ++kk2) {
                    float4 w = *(const float4*)&Wt[0][k2 * 2 + kk2][tx * 4];
                    #pragma unroll
                    for (int r = 0; r < 8; ++r) {
                        float avv = kk2 ? a2[r].y : a2[r].x;
                        acc[r][0] += avv * w.x;
                        acc[r][1] += avv * w.y;
                        acc[r][2] += avv * w.z;
                        acc[r][3] += avv * w.w;
                    }
                }
            }
            __syncthreads();
        }
    }

    float4 bv = *(const float4*)(bvec + tx * 4);
    #pragma unroll
    for (int r = 0; r < 8; r++) {
        int row = m0 + ty * 8 + r;
        if (row >= N_NODES) break;
        float4 o = make_float4(acc[r][0] + bv.x, acc[r][1] + bv.y,
                               acc[r][2] + bv.z, acc[r][3] + bv.w);
        *(float4*)(PQ + (size_t)row * 256 + half * 128 + tx * 4) = o;
    }
}

// ---------------------------------------------------------------------------
// K2: one wave per (b,t). All 21 row-gathers issued into registers up front,
// then ballots, then sparse weight-row walks with independent accumulators.
// ---------------------------------------------------------------------------
__device__ __forceinline__ void mask_walk(unsigned long long m, int par,
                                          const float* __restrict__ w,
                                          int lane, float& acc)
{
    while (m) {
        int i = __builtin_ctzll(m);
        m &= m - 1;
        acc += w[(size_t)(2 * i + par) * H2 + lane];
    }
}

template <int MODE>
__global__ __launch_bounds__(256) void k2_step(
    const float* __restrict__ x,
    const int* __restrict__ nodes, const int* __restrict__ nbr1,
    const int* __restrict__ nbr2,
    const float* __restrict__ w_l0, const float* __restrict__ b_l0,
    const float* __restrict__ w_r0, const float* __restrict__ b_r0,
    const float* __restrict__ w_l1, const float* __restrict__ b_l1,
    const float* __restrict__ w_r1, const float* __restrict__ b_r1,
    const float* __restrict__ PQ,
    unsigned long long* __restrict__ bits)
{
    const int lane = threadIdx.x & 63;
    const int wv   = threadIdx.x >> 6;
    const int gw   = __builtin_amdgcn_readfirstlane((int)(blockIdx.x * 4 + wv));
    const int b    = gw >> 3;
    const int t    = gw & 7;
    const int c2   = lane * 2;

    if (MODE == 0) {
        const int i_self = nodes[b];
        int i1[S1];
        #pragma unroll
        for (int s = 0; s < S1; s++) i1[s] = nbr1[t * (B * S1) + b * S1 + s];
        int i2[S1 * S2];
        #pragma unroll
        for (int q = 0; q < S1 * S2; q++) i2[q] = nbr2[t * (B * S1 * S2) + b * S1 * S2 + q];

        float2 sp = *(const float2*)(PQ + (size_t)i_self * 256 + c2);
        float2 p1[S1], q1[S1], q2[S1 * S2];
        #pragma unroll
        for (int s = 0; s < S1; s++)
            p1[s] = *(const float2*)(PQ + (size_t)i1[s] * 256 + c2);
        #pragma unroll
        for (int s = 0; s < S1; s++)
            q1[s] = *(const float2*)(PQ + (size_t)i1[s] * 256 + 128 + c2);
        #pragma unroll
        for (int u = 0; u < S1 * S2; u++)
            q2[u] = *(const float2*)(PQ + (size_t)i2[u] * 256 + 128 + c2);

        float qsx = 0.f, qsy = 0.f;
        #pragma unroll
        for (int s = 0; s < S1; s++) { qsx += q1[s].x; qsy += q1[s].y; }
        unsigned long long mLx = __ballot(sp.x + 0.2f * qsx >= 1.0f);
        unsigned long long mLy = __ballot(sp.y + 0.2f * qsy >= 1.0f);
        unsigned long long mRx[S1], mRy[S1];
        #pragma unroll
        for (int r = 0; r < S1; r++) {
            float cx = p1[r].x + 0.5f * (q2[2 * r].x + q2[2 * r + 1].x);
            float cy = p1[r].y + 0.5f * (q2[2 * r].y + q2[2 * r + 1].y);
            mRx[r] = __ballot(cx >= 1.0f);
            mRy[r] = __ballot(cy >= 1.0f);
        }

        float aL0 = 0.f, aL1 = 0.f;
        float aR0 = 0.f, aR1 = 0.f, aR2 = 0.f, aR3 = 0.f;
        mask_walk(mLx, 0, w_l1, lane, aL0);
        mask_walk(mLy, 1, w_l1, lane, aL1);
        mask_walk(mRx[0], 0, w_r1, lane, aR0);
        mask_walk(mRy[0], 1, w_r1, lane, aR1);
        mask_walk(mRx[1], 0, w_r1, lane, aR2);
        mask_walk(mRy[1], 1, w_r1, lane, aR3);
        mask_walk(mRx[2], 0, w_r1, lane, aR0);
        mask_walk(mRy[2], 1, w_r1, lane, aR1);
        mask_walk(mRx[3], 0, w_r1, lane, aR2);
        mask_walk(mRy[3], 1, w_r1, lane, aR3);
        mask_walk(mRx[4], 0, w_r1, lane, aR0);
        mask_walk(mRy[4], 1, w_r1, lane, aR1);

        float cur1 = (aL0 + aL1) + 0.2f * ((aR0 + aR1) + (aR2 + aR3))
                   + b_l1[lane] + b_r1[lane];
        unsigned long long sb = __ballot(cur1 >= 1.0f);
        if (lane == 0) bits[(size_t)b * T + t] = sb;
    } else {
        __shared__ float a_lds[4][F];
        __shared__ float n_lds[4][F];
        const int i_self = nodes[b];
        int i1[S1];
        #pragma unroll
        for (int s = 0; s < S1; s++) i1[s] = nbr1[t * (B * S1) + b * S1 + s];
        int i2[S1 * S2];
        #pragma unroll
        for (int q = 0; q < S1 * S2; q++) i2[q] = nbr2[t * (B * S1 * S2) + b * S1 * S2 + q];

        float accL = 0.f, accR = 0.f;
        const float b0x = b_l0[c2] + b_r0[c2];
        const float b0y = b_l0[c2 + 1] + b_r0[c2 + 1];
        float nsx = 0.f, nsy = 0.f;
        #pragma unroll 1
        for (int r = 1; r < 6; r++) {
            const float* ar = x + (size_t)i1[r - 1] * F;
            float ax = ar[c2], ay = ar[c2 + 1];
            nsx += ax; nsy += ay;
            const float* ch0 = x + (size_t)i2[(r - 1) * 2] * F;
            const float* ch1 = x + (size_t)i2[(r - 1) * 2 + 1] * F;
            float nx = 0.5f * (ch0[c2]     + ch1[c2]);
            float ny = 0.5f * (ch0[c2 + 1] + ch1[c2 + 1]);
            a_lds[wv][c2] = ax; a_lds[wv][c2 + 1] = ay;
            n_lds[wv][c2] = nx; n_lds[wv][c2 + 1] = ny;
            float cx = b0x, cy = b0y;
            #pragma unroll 4
            for (int k = 0; k < F; k++) {
                float ak = a_lds[wv][k], nk = n_lds[wv][k];
                const float* wl = w_l0 + (size_t)k * H1 + c2;
                const float* wr = w_r0 + (size_t)k * H1 + c2;
                cx += ak * wl[0] + nk * wr[0];
                cy += ak * wl[1] + nk * wr[1];
            }
            mask_walk(__ballot(cx >= 1.0f), 0, w_r1, lane, accR);
            mask_walk(__ballot(cy >= 1.0f), 1, w_r1, lane, accR);
        }
        {
            const float* ar = x + (size_t)i_self * F;
            float ax = ar[c2], ay = ar[c2 + 1];
            a_lds[wv][c2] = ax; a_lds[wv][c2 + 1] = ay;
            n_lds[wv][c2] = 0.2f * nsx; n_lds[wv][c2 + 1] = 0.2f * nsy;
            float cx = b0x, cy = b0y;
            #pragma unroll 4
            for (int k = 0; k < F; k++) {
                float ak = a_lds[wv][k], nk = n_lds[wv][k];
                const float* wl = w_l0 + (size_t)k * H1 + c2;
                const float* wr = w_r0 + (size_t)k * H1 + c2;
                cx += ak * wl[0] + nk * wr[0];
                cy += ak * wl[1] + nk * wr[1];
            }
            mask_walk(__ballot(cx >= 1.0f), 0, w_l1, lane, accL);
            mask_walk(__ballot(cy >= 1.0f), 1, w_l1, lane, accL);
        }
        float cur1 = accL + 0.2f * accR + b_l1[lane] + b_r1[lane];
        unsigned long long sb = __ballot(cur1 >= 1.0f);
        if (lane == 0) bits[(size_t)b * T + t] = sb;
    }
}

// ---------------------------------------------------------------------------
// K3: out[b][c] = b_pool[c] + sum over set spike bits of w_pool[(t*64+j)][c]
// ---------------------------------------------------------------------------
__global__ __launch_bounds__(256) void k3_pool(
    const float* __restrict__ w_pool, const float* __restrict__ b_pool,
    const unsigned long long* __restrict__ bits, float* __restrict__ out)
{
    const int tid = threadIdx.x;
    const int c = tid & 31;
    const int g = tid >> 5;
    const int b = blockIdx.x * 8 + g;
    if (b >= B) return;
    float acc = b_pool[c];
    #pragma unroll
    for (int t = 0; t < T; t++) {
        unsigned long long m = bits[(size_t)b * T + t];
        while (m) {
            int j = __builtin_ctzll(m);
            m &= m - 1;
            acc += w_pool[(size_t)(t * H2 + j) * C + c];
        }
    }
    out[(size_t)b * C + c] = acc;
}

extern "C" void kernel_launch(void* const* d_in, const int* in_sizes, int n_in,
                              void* d_out, int out_size, void* d_ws, size_t ws_size,
                              hipStream_t stream)
{
    const float* x      = (const float*)d_in[0];
    const int*   nodes  = (const int*)d_in[1];
    const int*   nbr1   = (const int*)d_in[2];
    const int*   nbr2   = (const int*)d_in[3];
    const float* w_l0   = (const float*)d_in[4];
    const float* b_l0   = (const float*)d_in[5];
    const float* w_r0   = (const float*)d_in[6];
    const float* b_r0   = (const float*)d_in[7];
    const float* w_l1   = (const float*)d_in[8];
    const float* b_l1   = (const float*)d_in[9];
    const float* w_r1   = (const float*)d_in[10];
    const float* b_r1   = (const float*)d_in[11];
    const float* w_pool = (const float*)d_in[12];
    const float* b_pool = (const float*)d_in[13];
    float* out = (float*)d_out;

    const size_t pq_bytes   = (size_t)N_NODES * 256 * sizeof(float);
    const size_t bits_bytes = (size_t)B * T * sizeof(unsigned long long);

    if (ws_size >= pq_bytes + bits_bytes) {
        float* PQ = (float*)d_ws;
        unsigned long long* bits = (unsigned long long*)((char*)d_ws + pq_bytes);
        const int nrb = (N_NODES + 63) / 64;       // row blocks
        k1_pq<<<nrb * 2, 256, 0, stream>>>(x, w_l0, b_l0, w_r0, b_r0, PQ);
        k2_step<0><<<(B * T) / 4, 256, 0, stream>>>(x, nodes, nbr1, nbr2,
            w_l0, b_l0, w_r0, b_r0, w_l1, b_l1, w_r1, b_r1, PQ, bits);
        k3_pool<<<B / 8, 256, 0, stream>>>(w_pool, b_pool, bits, out);
    } else {
        unsigned long long* bits = (unsigned long long*)d_ws;
        k2_step<1><<<(B * T) / 4, 256, 0, stream>>>(x, nodes, nbr1, nbr2,
            w_l0, b_l0, w_r0, b_r0, w_l1, b_l1, w_r1, b_r1, nullptr, bits);
        k3_pool<<<B / 8, 256, 0, stream>>>(w_pool, b_pool, bits, out);
    }
}

// Round 7
// 571.524 us; speedup vs baseline: 1.3537x; 1.3537x over previous
//
#include <hip/hip_runtime.h>
#include <hip/hip_bf16.h>
#include <stdint.h>

#define N_NODES 500000
#define F 128
#define B 20000
#define T 8
#define H1 128
#define H2 64
#define C 32
#define S1 5
#define S2 2

typedef __attribute__((ext_vector_type(8))) short s16x8;
typedef __attribute__((ext_vector_type(4))) float f32x4;

// round-to-nearest-even fp32 -> bf16 (bit-level, deterministic)
__device__ __forceinline__ unsigned short f2bf(float v) {
    unsigned int u = __builtin_bit_cast(unsigned int, v);
    unsigned int r = (u + 0x7fffu + ((u >> 16) & 1u)) >> 16;
    return (unsigned short)r;
}
__device__ __forceinline__ float bf2f(unsigned short u) {
    unsigned int x = ((unsigned int)u) << 16;
    return __builtin_bit_cast(float, x);
}

// ---------------------------------------------------------------------------
// K0: split [w_l0 | w_r0] (128x256 fp32) into bf16 hi/lo, TRANSPOSED to
// [n][k] so MFMA B-fragments (8 contiguous k per lane) are single b128 loads.
// Written into the d_ws "bits" region (only needed before K2 runs).
// ---------------------------------------------------------------------------
__global__ __launch_bounds__(256) void k0_wsplit(
    const float* __restrict__ wl, const float* __restrict__ wr,
    unsigned short* __restrict__ whi, unsigned short* __restrict__ wlo)
{
    int idx = blockIdx.x * 256 + threadIdx.x;     // [n][k], 256*128 total
    if (idx >= 256 * 128) return;
    int n = idx >> 7, k = idx & 127;
    float v = (n < 128) ? wl[(size_t)k * 128 + n] : wr[(size_t)k * 128 + (n - 128)];
    unsigned short h = f2bf(v);
    whi[idx] = h;
    wlo[idx] = f2bf(v - bf2f(h));
}

// ---------------------------------------------------------------------------
// K1: PQ[n] = [ x[n]@w_l0 + b_l0 | x[n]@w_r0 + b_r0 ]  via bf16x3 split-MFMA.
// BM=64 rows/block, 4 waves each owning a 64-col quarter of N=256.
// Per k-step (K=32): all 256 threads cooperatively split the 64x32 fp32
// A-slab into bf16 hi/lo in LDS (padded rows); each wave then loads its
// A/B fragments and issues 48 mfma_f32_16x16x32_bf16 (HH, HL, LH passes),
// accumulating fp32. Error ~3e-6 in cur0; layer-1 threshold is ~5 sigma out
// so spike-flip propagation is negligible (see R6 analysis).
// Fragment layouts: A row=l&15, k=8*(l>>4)+j; B (stored [n][k]) n=l&15,
// k=8*(l>>4)+j; D col=l&15, row=4*(l>>4)+j (m89-verified).
// ---------------------------------------------------------------------------
__global__ __launch_bounds__(256) void k1_mfma(
    const float* __restrict__ x,
    const unsigned short* __restrict__ whi,
    const unsigned short* __restrict__ wlo,
    const float* __restrict__ b_l0, const float* __restrict__ b_r0,
    float* __restrict__ PQ)
{
    __shared__ unsigned short Ahi[64][40];   // pad 32->40 (rows 80B, 16B-aligned)
    __shared__ unsigned short Alo[64][40];

    const int tid  = threadIdx.x;
    const int wv   = tid >> 6;               // wave 0..3 -> cols wv*64..+63
    const int lane = tid & 63;
    const int fl   = lane & 15;
    const int fg   = lane >> 4;
    const int m0   = blockIdx.x * 64;

    // split assignment: thread -> (row, 8-float chunk)
    const int srow = tid >> 2;
    const int sc   = tid & 3;
    const int rowc = min(m0 + srow, N_NODES - 1);   // clamp for tail block
    const float* xbase = x + (size_t)rowc * F + sc * 8;

    // per-nf bias (col = wv*64 + 16*nf + fl, fixed per thread)
    float bias_nf[4];
    #pragma unroll
    for (int nf = 0; nf < 4; ++nf) {
        int cc = wv * 64 + 16 * nf + fl;
        bias_nf[nf] = (cc < 128) ? b_l0[cc] : b_r0[cc - 128];
    }

    f32x4 acc[4][4];
    #pragma unroll
    for (int mf = 0; mf < 4; ++mf)
        #pragma unroll
        for (int nf = 0; nf < 4; ++nf)
            acc[mf][nf] = (f32x4){0.f, 0.f, 0.f, 0.f};

    for (int ks = 0; ks < 4; ++ks) {
        // ---- split phase: x[*, ks*32 .. +31] -> Ahi/Alo (bf16) ----
        float4 v0 = *(const float4*)(xbase + ks * 32);
        float4 v1 = *(const float4*)(xbase + ks * 32 + 4);
        float xv[8] = {v0.x, v0.y, v0.z, v0.w, v1.x, v1.y, v1.z, v1.w};
        s16x8 ph, pl;
        #pragma unroll
        for (int j = 0; j < 8; ++j) {
            unsigned short h = f2bf(xv[j]);
            ph[j] = (short)h;
            pl[j] = (short)f2bf(xv[j] - bf2f(h));
        }
        *(s16x8*)&Ahi[srow][sc * 8] = ph;
        *(s16x8*)&Alo[srow][sc * 8] = pl;
        __syncthreads();

        // ---- B fragments (global, L2-hot 128KB) ----
        s16x8 bh[4], bl[4];
        #pragma unroll
        for (int nf = 0; nf < 4; ++nf) {
            size_t n = (size_t)(wv * 64 + 16 * nf + fl);
            bh[nf] = *(const s16x8*)(whi + n * 128 + ks * 32 + fg * 8);
            bl[nf] = *(const s16x8*)(wlo + n * 128 + ks * 32 + fg * 8);
        }
        // ---- A fragments (LDS) ----
        s16x8 ah[4], al[4];
        #pragma unroll
        for (int mf = 0; mf < 4; ++mf) {
            ah[mf] = *(const s16x8*)&Ahi[16 * mf + fl][fg * 8];
            al[mf] = *(const s16x8*)&Alo[16 * mf + fl][fg * 8];
        }
        // ---- 3-pass MFMA ----
        #pragma unroll
        for (int mf = 0; mf < 4; ++mf)
            #pragma unroll
            for (int nf = 0; nf < 4; ++nf) {
                acc[mf][nf] = __builtin_amdgcn_mfma_f32_16x16x32_bf16(
                    ah[mf], bh[nf], acc[mf][nf], 0, 0, 0);
                acc[mf][nf] = __builtin_amdgcn_mfma_f32_16x16x32_bf16(
                    ah[mf], bl[nf], acc[mf][nf], 0, 0, 0);
                acc[mf][nf] = __builtin_amdgcn_mfma_f32_16x16x32_bf16(
                    al[mf], bh[nf], acc[mf][nf], 0, 0, 0);
            }
        __syncthreads();
    }

    // ---- store: D col=fl (per nf), row = 16*mf + 4*fg + j ----
    #pragma unroll
    for (int mf = 0; mf < 4; ++mf) {
        #pragma unroll
        for (int j = 0; j < 4; ++j) {
            int row = m0 + 16 * mf + 4 * fg + j;
            if (row < N_NODES) {
                #pragma unroll
                for (int nf = 0; nf < 4; ++nf) {
                    int col = wv * 64 + 16 * nf + fl;
                    PQ[(size_t)row * 256 + col] = acc[mf][nf][j] + bias_nf[nf];
                }
            }
        }
    }
}

// ---------------------------------------------------------------------------
// K2: one wave per (b,t). All 21 row-gathers issued into registers up front,
// then ballots, then sparse weight-row walks with independent accumulators.
// ---------------------------------------------------------------------------
__device__ __forceinline__ void mask_walk(unsigned long long m, int par,
                                          const float* __restrict__ w,
                                          int lane, float& acc)
{
    while (m) {
        int i = __builtin_ctzll(m);
        m &= m - 1;
        acc += w[(size_t)(2 * i + par) * H2 + lane];
    }
}

template <int MODE>
__global__ __launch_bounds__(256) void k2_step(
    const float* __restrict__ x,
    const int* __restrict__ nodes, const int* __restrict__ nbr1,
    const int* __restrict__ nbr2,
    const float* __restrict__ w_l0, const float* __restrict__ b_l0,
    const float* __restrict__ w_r0, const float* __restrict__ b_r0,
    const float* __restrict__ w_l1, const float* __restrict__ b_l1,
    const float* __restrict__ w_r1, const float* __restrict__ b_r1,
    const float* __restrict__ PQ,
    unsigned long long* __restrict__ bits)
{
    const int lane = threadIdx.x & 63;
    const int wv   = threadIdx.x >> 6;
    const int gw   = __builtin_amdgcn_readfirstlane((int)(blockIdx.x * 4 + wv));
    const int b    = gw >> 3;
    const int t    = gw & 7;
    const int c2   = lane * 2;

    if (MODE == 0) {
        const int i_self = nodes[b];
        int i1[S1];
        #pragma unroll
        for (int s = 0; s < S1; s++) i1[s] = nbr1[t * (B * S1) + b * S1 + s];
        int i2[S1 * S2];
        #pragma unroll
        for (int q = 0; q < S1 * S2; q++) i2[q] = nbr2[t * (B * S1 * S2) + b * S1 * S2 + q];

        float2 sp = *(const float2*)(PQ + (size_t)i_self * 256 + c2);
        float2 p1[S1], q1[S1], q2[S1 * S2];
        #pragma unroll
        for (int s = 0; s < S1; s++)
            p1[s] = *(const float2*)(PQ + (size_t)i1[s] * 256 + c2);
        #pragma unroll
        for (int s = 0; s < S1; s++)
            q1[s] = *(const float2*)(PQ + (size_t)i1[s] * 256 + 128 + c2);
        #pragma unroll
        for (int u = 0; u < S1 * S2; u++)
            q2[u] = *(const float2*)(PQ + (size_t)i2[u] * 256 + 128 + c2);

        float qsx = 0.f, qsy = 0.f;
        #pragma unroll
        for (int s = 0; s < S1; s++) { qsx += q1[s].x; qsy += q1[s].y; }
        unsigned long long mLx = __ballot(sp.x + 0.2f * qsx >= 1.0f);
        unsigned long long mLy = __ballot(sp.y + 0.2f * qsy >= 1.0f);
        unsigned long long mRx[S1], mRy[S1];
        #pragma unroll
        for (int r = 0; r < S1; r++) {
            float cx = p1[r].x + 0.5f * (q2[2 * r].x + q2[2 * r + 1].x);
            float cy = p1[r].y + 0.5f * (q2[2 * r].y + q2[2 * r + 1].y);
            mRx[r] = __ballot(cx >= 1.0f);
            mRy[r] = __ballot(cy >= 1.0f);
        }

        float aL0 = 0.f, aL1 = 0.f;
        float aR0 = 0.f, aR1 = 0.f, aR2 = 0.f, aR3 = 0.f;
        mask_walk(mLx, 0, w_l1, lane, aL0);
        mask_walk(mLy, 1, w_l1, lane, aL1);
        mask_walk(mRx[0], 0, w_r1, lane, aR0);
        mask_walk(mRy[0], 1, w_r1, lane, aR1);
        mask_walk(mRx[1], 0, w_r1, lane, aR2);
        mask_walk(mRy[1], 1, w_r1, lane, aR3);
        mask_walk(mRx[2], 0, w_r1, lane, aR0);
        mask_walk(mRy[2], 1, w_r1, lane, aR1);
        mask_walk(mRx[3], 0, w_r1, lane, aR2);
        mask_walk(mRy[3], 1, w_r1, lane, aR3);
        mask_walk(mRx[4], 0, w_r1, lane, aR0);
        mask_walk(mRy[4], 1, w_r1, lane, aR1);

        float cur1 = (aL0 + aL1) + 0.2f * ((aR0 + aR1) + (aR2 + aR3))
                   + b_l1[lane] + b_r1[lane];
        unsigned long long sb = __ballot(cur1 >= 1.0f);
        if (lane == 0) bits[(size_t)b * T + t] = sb;
    } else {
        __shared__ float a_lds[4][F];
        __shared__ float n_lds[4][F];
        const int i_self = nodes[b];
        int i1[S1];
        #pragma unroll
        for (int s = 0; s < S1; s++) i1[s] = nbr1[t * (B * S1) + b * S1 + s];
        int i2[S1 * S2];
        #pragma unroll
        for (int q = 0; q < S1 * S2; q++) i2[q] = nbr2[t * (B * S1 * S2) + b * S1 * S2 + q];

        float accL = 0.f, accR = 0.f;
        const float b0x = b_l0[c2] + b_r0[c2];
        const float b0y = b_l0[c2 + 1] + b_r0[c2 + 1];
        float nsx = 0.f, nsy = 0.f;
        #pragma unroll 1
        for (int r = 1; r < 6; r++) {
            const float* ar = x + (size_t)i1[r - 1] * F;
            float ax = ar[c2], ay = ar[c2 + 1];
            nsx += ax; nsy += ay;
            const float* ch0 = x + (size_t)i2[(r - 1) * 2] * F;
            const float* ch1 = x + (size_t)i2[(r - 1) * 2 + 1] * F;
            float nx = 0.5f * (ch0[c2]     + ch1[c2]);
            float ny = 0.5f * (ch0[c2 + 1] + ch1[c2 + 1]);
            a_lds[wv][c2] = ax; a_lds[wv][c2 + 1] = ay;
            n_lds[wv][c2] = nx; n_lds[wv][c2 + 1] = ny;
            float cx = b0x, cy = b0y;
            #pragma unroll 4
            for (int k = 0; k < F; k++) {
                float ak = a_lds[wv][k], nk = n_lds[wv][k];
                const float* wl = w_l0 + (size_t)k * H1 + c2;
                const float* wr = w_r0 + (size_t)k * H1 + c2;
                cx += ak * wl[0] + nk * wr[0];
                cy += ak * wl[1] + nk * wr[1];
            }
            mask_walk(__ballot(cx >= 1.0f), 0, w_r1, lane, accR);
            mask_walk(__ballot(cy >= 1.0f), 1, w_r1, lane, accR);
        }
        {
            const float* ar = x + (size_t)i_self * F;
            float ax = ar[c2], ay = ar[c2 + 1];
            a_lds[wv][c2] = ax; a_lds[wv][c2 + 1] = ay;
            n_lds[wv][c2] = 0.2f * nsx; n_lds[wv][c2 + 1] = 0.2f * nsy;
            float cx = b0x, cy = b0y;
            #pragma unroll 4
            for (int k = 0; k < F; k++) {
                float ak = a_lds[wv][k], nk = n_lds[wv][k];
                const float* wl = w_l0 + (size_t)k * H1 + c2;
                const float* wr = w_r0 + (size_t)k * H1 + c2;
                cx += ak * wl[0] + nk * wr[0];
                cy += ak * wl[1] + nk * wr[1];
            }
            mask_walk(__ballot(cx >= 1.0f), 0, w_l1, lane, accL);
            mask_walk(__ballot(cy >= 1.0f), 1, w_l1, lane, accL);
        }
        float cur1 = accL + 0.2f * accR + b_l1[lane] + b_r1[lane];
        unsigned long long sb = __ballot(cur1 >= 1.0f);
        if (lane == 0) bits[(size_t)b * T + t] = sb;
    }
}

// ---------------------------------------------------------------------------
// K3: out[b][c] = b_pool[c] + sum over set spike bits of w_pool[(t*64+j)][c]
// ---------------------------------------------------------------------------
__global__ __launch_bounds__(256) void k3_pool(
    const float* __restrict__ w_pool, const float* __restrict__ b_pool,
    const unsigned long long* __restrict__ bits, float* __restrict__ out)
{
    const int tid = threadIdx.x;
    const int c = tid & 31;
    const int g = tid >> 5;
    const int b = blockIdx.x * 8 + g;
    if (b >= B) return;
    float acc = b_pool[c];
    #pragma unroll
    for (int t = 0; t < T; t++) {
        unsigned long long m = bits[(size_t)b * T + t];
        while (m) {
            int j = __builtin_ctzll(m);
            m &= m - 1;
            acc += w_pool[(size_t)(t * H2 + j) * C + c];
        }
    }
    out[(size_t)b * C + c] = acc;
}

extern "C" void kernel_launch(void* const* d_in, const int* in_sizes, int n_in,
                              void* d_out, int out_size, void* d_ws, size_t ws_size,
                              hipStream_t stream)
{
    const float* x      = (const float*)d_in[0];
    const int*   nodes  = (const int*)d_in[1];
    const int*   nbr1   = (const int*)d_in[2];
    const int*   nbr2   = (const int*)d_in[3];
    const float* w_l0   = (const float*)d_in[4];
    const float* b_l0   = (const float*)d_in[5];
    const float* w_r0   = (const float*)d_in[6];
    const float* b_r0   = (const float*)d_in[7];
    const float* w_l1   = (const float*)d_in[8];
    const float* b_l1   = (const float*)d_in[9];
    const float* w_r1   = (const float*)d_in[10];
    const float* b_r1   = (const float*)d_in[11];
    const float* w_pool = (const float*)d_in[12];
    const float* b_pool = (const float*)d_in[13];
    float* out = (float*)d_out;

    const size_t pq_bytes   = (size_t)N_NODES * 256 * sizeof(float);          // 512 MB
    const size_t bits_bytes = (size_t)B * T * sizeof(unsigned long long);     // 1.28 MB
    // Wt hi/lo (128KB + 128KB... actually 64KB each) live in the bits region:
    // needed only by k0/k1, which complete before k2 writes bits. Total ws
    // requirement is unchanged from the proven pq+bits config.

    if (ws_size >= pq_bytes + bits_bytes) {
        float* PQ = (float*)d_ws;
        unsigned short* whi = (unsigned short*)((char*)d_ws + pq_bytes);
        unsigned short* wlo = whi + 256 * 128;
        unsigned long long* bits = (unsigned long long*)((char*)d_ws + pq_bytes);

        k0_wsplit<<<128, 256, 0, stream>>>(w_l0, w_r0, whi, wlo);
        k1_mfma<<<(N_NODES + 63) / 64, 256, 0, stream>>>(x, whi, wlo, b_l0, b_r0, PQ);
        k2_step<0><<<(B * T) / 4, 256, 0, stream>>>(x, nodes, nbr1, nbr2,
            w_l0, b_l0, w_r0, b_r0, w_l1, b_l1, w_r1, b_r1, PQ, bits);
        k3_pool<<<B / 8, 256, 0, stream>>>(w_pool, b_pool, bits, out);
    } else {
        unsigned long long* bits = (unsigned long long*)d_ws;
        k2_step<1><<<(B * T) / 4, 256, 0, stream>>>(x, nodes, nbr1, nbr2,
            w_l0, b_l0, w_r0, b_r0, w_l1, b_l1, w_r1, b_r1, nullptr, bits);
        k3_pool<<<B / 8, 256, 0, stream>>>(w_pool, b_pool, bits, out);
    }
}

// Round 8
// 559.179 us; speedup vs baseline: 1.3836x; 1.0221x over previous
//
#include <hip/hip_runtime.h>
#include <hip/hip_bf16.h>
#include <stdint.h>

#define N_NODES 500000
#define F 128
#define B 20000
#define T 8
#define H1 128
#define H2 64
#define C 32
#define S1 5
#define S2 2

typedef __attribute__((ext_vector_type(8))) short s16x8;
typedef __attribute__((ext_vector_type(4))) float f32x4;

// round-to-nearest-even fp32 -> bf16 (bit-level, deterministic)
__device__ __forceinline__ unsigned short f2bf(float v) {
    unsigned int u = __builtin_bit_cast(unsigned int, v);
    unsigned int r = (u + 0x7fffu + ((u >> 16) & 1u)) >> 16;
    return (unsigned short)r;
}
__device__ __forceinline__ float bf2f(unsigned short u) {
    unsigned int x = ((unsigned int)u) << 16;
    return __builtin_bit_cast(float, x);
}

// ---------------------------------------------------------------------------
// K0: split [w_l0 | w_r0] (128x256 fp32) into bf16 hi/lo, TRANSPOSED to
// [n][k] so MFMA B-fragments (8 contiguous k per lane) are single b128 loads.
// Lives in the d_ws "bits" region (consumed before K2 writes bits).
// ---------------------------------------------------------------------------
__global__ __launch_bounds__(256) void k0_wsplit(
    const float* __restrict__ wl, const float* __restrict__ wr,
    unsigned short* __restrict__ whi, unsigned short* __restrict__ wlo)
{
    int idx = blockIdx.x * 256 + threadIdx.x;     // [n][k], 256*128 total
    if (idx >= 256 * 128) return;
    int n = idx >> 7, k = idx & 127;
    float v = (n < 128) ? wl[(size_t)k * 128 + n] : wr[(size_t)k * 128 + (n - 128)];
    unsigned short h = f2bf(v);
    whi[idx] = h;
    wlo[idx] = f2bf(v - bf2f(h));
}

// ---------------------------------------------------------------------------
// K1: PQ[n] = [ x[n]@w_l0 + b_l0 | x[n]@w_r0 + b_r0 ]  via bf16x3 split-MFMA.
// BM=64 rows/block, 4 waves each owning a 64-col quarter of N=256.
// v2 (R7): split the WHOLE 64x128 A-slab into LDS once (Ahi/Alo, padded
// rows), ONE barrier, then a fully unrolled barrier-free 4-ks MFMA loop.
// R7 lesson: per-ks split with 2 barriers/ks serialized split<->MFMA and
// cost ~80us over the HBM floor.
// Fragment layouts (m89-verified): A row=l&15, k=8*(l>>4)+j; B (stored
// [n][k]) n=l&15, k=8*(l>>4)+j; D col=l&15, row=4*(l>>4)+j.
// ---------------------------------------------------------------------------
__global__ __launch_bounds__(256) void k1_mfma(
    const float* __restrict__ x,
    const unsigned short* __restrict__ whi,
    const unsigned short* __restrict__ wlo,
    const float* __restrict__ b_l0, const float* __restrict__ b_r0,
    float* __restrict__ PQ)
{
    __shared__ unsigned short Ahi[64][136];   // 128 + 8 pad (rows 272B)
    __shared__ unsigned short Alo[64][136];

    const int tid  = threadIdx.x;
    const int wv   = tid >> 6;               // wave 0..3 -> cols wv*64..+63
    const int lane = tid & 63;
    const int fl   = lane & 15;
    const int fg   = lane >> 4;
    const int m0   = blockIdx.x * 64;

    // ---- split phase: thread (row, 32-col segment) ----
    const int srow = tid >> 2;                // 0..63
    const int sc0  = (tid & 3) * 32;          // 0,32,64,96
    const int rowc = min(m0 + srow, N_NODES - 1);   // clamp for tail block
    const float* xbase = x + (size_t)rowc * F + sc0;

    #pragma unroll
    for (int c = 0; c < 4; ++c) {
        float4 v0 = *(const float4*)(xbase + c * 8);
        float4 v1 = *(const float4*)(xbase + c * 8 + 4);
        float xv[8] = {v0.x, v0.y, v0.z, v0.w, v1.x, v1.y, v1.z, v1.w};
        s16x8 ph, pl;
        #pragma unroll
        for (int j = 0; j < 8; ++j) {
            unsigned short h = f2bf(xv[j]);
            ph[j] = (short)h;
            pl[j] = (short)f2bf(xv[j] - bf2f(h));
        }
        *(s16x8*)&Ahi[srow][sc0 + c * 8] = ph;
        *(s16x8*)&Alo[srow][sc0 + c * 8] = pl;
    }
    __syncthreads();

    // per-nf bias (col = wv*64 + 16*nf + fl, fixed per thread)
    float bias_nf[4];
    #pragma unroll
    for (int nf = 0; nf < 4; ++nf) {
        int cc = wv * 64 + 16 * nf + fl;
        bias_nf[nf] = (cc < 128) ? b_l0[cc] : b_r0[cc - 128];
    }

    f32x4 acc[4][4];
    #pragma unroll
    for (int mf = 0; mf < 4; ++mf)
        #pragma unroll
        for (int nf = 0; nf < 4; ++nf)
            acc[mf][nf] = (f32x4){0.f, 0.f, 0.f, 0.f};

    // ---- barrier-free MFMA phase ----
    #pragma unroll
    for (int ks = 0; ks < 4; ++ks) {
        // B fragments (global, L2-hot 128KB)
        s16x8 bh[4], bl[4];
        #pragma unroll
        for (int nf = 0; nf < 4; ++nf) {
            size_t n = (size_t)(wv * 64 + 16 * nf + fl);
            bh[nf] = *(const s16x8*)(whi + n * 128 + ks * 32 + fg * 8);
            bl[nf] = *(const s16x8*)(wlo + n * 128 + ks * 32 + fg * 8);
        }
        // A fragments (LDS)
        s16x8 ah[4], al[4];
        #pragma unroll
        for (int mf = 0; mf < 4; ++mf) {
            ah[mf] = *(const s16x8*)&Ahi[16 * mf + fl][ks * 32 + fg * 8];
            al[mf] = *(const s16x8*)&Alo[16 * mf + fl][ks * 32 + fg * 8];
        }
        // 3-pass MFMA (HH, HL, LH)
        #pragma unroll
        for (int mf = 0; mf < 4; ++mf)
            #pragma unroll
            for (int nf = 0; nf < 4; ++nf) {
                acc[mf][nf] = __builtin_amdgcn_mfma_f32_16x16x32_bf16(
                    ah[mf], bh[nf], acc[mf][nf], 0, 0, 0);
                acc[mf][nf] = __builtin_amdgcn_mfma_f32_16x16x32_bf16(
                    ah[mf], bl[nf], acc[mf][nf], 0, 0, 0);
                acc[mf][nf] = __builtin_amdgcn_mfma_f32_16x16x32_bf16(
                    al[mf], bh[nf], acc[mf][nf], 0, 0, 0);
            }
    }

    // ---- store: D col=fl (per nf), row = 16*mf + 4*fg + j ----
    #pragma unroll
    for (int mf = 0; mf < 4; ++mf) {
        #pragma unroll
        for (int j = 0; j < 4; ++j) {
            int row = m0 + 16 * mf + 4 * fg + j;
            if (row < N_NODES) {
                #pragma unroll
                for (int nf = 0; nf < 4; ++nf) {
                    int col = wv * 64 + 16 * nf + fl;
                    PQ[(size_t)row * 256 + col] = acc[mf][nf][j] + bias_nf[nf];
                }
            }
        }
    }
}

// ---------------------------------------------------------------------------
// K2: one wave per (b,t). All 21 row-gathers issued into registers up front,
// then ballots, then sparse weight-row walks with independent accumulators.
// ---------------------------------------------------------------------------
__device__ __forceinline__ void mask_walk(unsigned long long m, int par,
                                          const float* __restrict__ w,
                                          int lane, float& acc)
{
    while (m) {
        int i = __builtin_ctzll(m);
        m &= m - 1;
        acc += w[(size_t)(2 * i + par) * H2 + lane];
    }
}

template <int MODE>
__global__ __launch_bounds__(256) void k2_step(
    const float* __restrict__ x,
    const int* __restrict__ nodes, const int* __restrict__ nbr1,
    const int* __restrict__ nbr2,
    const float* __restrict__ w_l0, const float* __restrict__ b_l0,
    const float* __restrict__ w_r0, const float* __restrict__ b_r0,
    const float* __restrict__ w_l1, const float* __restrict__ b_l1,
    const float* __restrict__ w_r1, const float* __restrict__ b_r1,
    const float* __restrict__ PQ,
    unsigned long long* __restrict__ bits)
{
    const int lane = threadIdx.x & 63;
    const int wv   = threadIdx.x >> 6;
    const int gw   = __builtin_amdgcn_readfirstlane((int)(blockIdx.x * 4 + wv));
    const int b    = gw >> 3;
    const int t    = gw & 7;
    const int c2   = lane * 2;

    if (MODE == 0) {
        const int i_self = nodes[b];
        int i1[S1];
        #pragma unroll
        for (int s = 0; s < S1; s++) i1[s] = nbr1[t * (B * S1) + b * S1 + s];
        int i2[S1 * S2];
        #pragma unroll
        for (int q = 0; q < S1 * S2; q++) i2[q] = nbr2[t * (B * S1 * S2) + b * S1 * S2 + q];

        float2 sp = *(const float2*)(PQ + (size_t)i_self * 256 + c2);
        float2 p1[S1], q1[S1], q2[S1 * S2];
        #pragma unroll
        for (int s = 0; s < S1; s++)
            p1[s] = *(const float2*)(PQ + (size_t)i1[s] * 256 + c2);
        #pragma unroll
        for (int s = 0; s < S1; s++)
            q1[s] = *(const float2*)(PQ + (size_t)i1[s] * 256 + 128 + c2);
        #pragma unroll
        for (int u = 0; u < S1 * S2; u++)
            q2[u] = *(const float2*)(PQ + (size_t)i2[u] * 256 + 128 + c2);

        float qsx = 0.f, qsy = 0.f;
        #pragma unroll
        for (int s = 0; s < S1; s++) { qsx += q1[s].x; qsy += q1[s].y; }
        unsigned long long mLx = __ballot(sp.x + 0.2f * qsx >= 1.0f);
        unsigned long long mLy = __ballot(sp.y + 0.2f * qsy >= 1.0f);
        unsigned long long mRx[S1], mRy[S1];
        #pragma unroll
        for (int r = 0; r < S1; r++) {
            float cx = p1[r].x + 0.5f * (q2[2 * r].x + q2[2 * r + 1].x);
            float cy = p1[r].y + 0.5f * (q2[2 * r].y + q2[2 * r + 1].y);
            mRx[r] = __ballot(cx >= 1.0f);
            mRy[r] = __ballot(cy >= 1.0f);
        }

        float aL0 = 0.f, aL1 = 0.f;
        float aR0 = 0.f, aR1 = 0.f, aR2 = 0.f, aR3 = 0.f;
        mask_walk(mLx, 0, w_l1, lane, aL0);
        mask_walk(mLy, 1, w_l1, lane, aL1);
        mask_walk(mRx[0], 0, w_r1, lane, aR0);
        mask_walk(mRy[0], 1, w_r1, lane, aR1);
        mask_walk(mRx[1], 0, w_r1, lane, aR2);
        mask_walk(mRy[1], 1, w_r1, lane, aR3);
        mask_walk(mRx[2], 0, w_r1, lane, aR0);
        mask_walk(mRy[2], 1, w_r1, lane, aR1);
        mask_walk(mRx[3], 0, w_r1, lane, aR2);
        mask_walk(mRy[3], 1, w_r1, lane, aR3);
        mask_walk(mRx[4], 0, w_r1, lane, aR0);
        mask_walk(mRy[4], 1, w_r1, lane, aR1);

        float cur1 = (aL0 + aL1) + 0.2f * ((aR0 + aR1) + (aR2 + aR3))
                   + b_l1[lane] + b_r1[lane];
        unsigned long long sb = __ballot(cur1 >= 1.0f);
        if (lane == 0) bits[(size_t)b * T + t] = sb;
    } else {
        __shared__ float a_lds[4][F];
        __shared__ float n_lds[4][F];
        const int i_self = nodes[b];
        int i1[S1];
        #pragma unroll
        for (int s = 0; s < S1; s++) i1[s] = nbr1[t * (B * S1) + b * S1 + s];
        int i2[S1 * S2];
        #pragma unroll
        for (int q = 0; q < S1 * S2; q++) i2[q] = nbr2[t * (B * S1 * S2) + b * S1 * S2 + q];

        float accL = 0.f, accR = 0.f;
        const float b0x = b_l0[c2] + b_r0[c2];
        const float b0y = b_l0[c2 + 1] + b_r0[c2 + 1];
        float nsx = 0.f, nsy = 0.f;
        #pragma unroll 1
        for (int r = 1; r < 6; r++) {
            const float* ar = x + (size_t)i1[r - 1] * F;
            float ax = ar[c2], ay = ar[c2 + 1];
            nsx += ax; nsy += ay;
            const float* ch0 = x + (size_t)i2[(r - 1) * 2] * F;
            const float* ch1 = x + (size_t)i2[(r - 1) * 2 + 1] * F;
            float nx = 0.5f * (ch0[c2]     + ch1[c2]);
            float ny = 0.5f * (ch0[c2 + 1] + ch1[c2 + 1]);
            a_lds[wv][c2] = ax; a_lds[wv][c2 + 1] = ay;
            n_lds[wv][c2] = nx; n_lds[wv][c2 + 1] = ny;
            float cx = b0x, cy = b0y;
            #pragma unroll 4
            for (int k = 0; k < F; k++) {
                float ak = a_lds[wv][k], nk = n_lds[wv][k];
                const float* wl = w_l0 + (size_t)k * H1 + c2;
                const float* wr = w_r0 + (size_t)k * H1 + c2;
                cx += ak * wl[0] + nk * wr[0];
                cy += ak * wl[1] + nk * wr[1];
            }
            mask_walk(__ballot(cx >= 1.0f), 0, w_r1, lane, accR);
            mask_walk(__ballot(cy >= 1.0f), 1, w_r1, lane, accR);
        }
        {
            const float* ar = x + (size_t)i_self * F;
            float ax = ar[c2], ay = ar[c2 + 1];
            a_lds[wv][c2] = ax; a_lds[wv][c2 + 1] = ay;
            n_lds[wv][c2] = 0.2f * nsx; n_lds[wv][c2 + 1] = 0.2f * nsy;
            float cx = b0x, cy = b0y;
            #pragma unroll 4
            for (int k = 0; k < F; k++) {
                float ak = a_lds[wv][k], nk = n_lds[wv][k];
                const float* wl = w_l0 + (size_t)k * H1 + c2;
                const float* wr = w_r0 + (size_t)k * H1 + c2;
                cx += ak * wl[0] + nk * wr[0];
                cy += ak * wl[1] + nk * wr[1];
            }
            mask_walk(__ballot(cx >= 1.0f), 0, w_l1, lane, accL);
            mask_walk(__ballot(cy >= 1.0f), 1, w_l1, lane, accL);
        }
        float cur1 = accL + 0.2f * accR + b_l1[lane] + b_r1[lane];
        unsigned long long sb = __ballot(cur1 >= 1.0f);
        if (lane == 0) bits[(size_t)b * T + t] = sb;
    }
}

// ---------------------------------------------------------------------------
// K3: out[b][c] = b_pool[c] + sum over set spike bits of w_pool[(t*64+j)][c]
// ---------------------------------------------------------------------------
__global__ __launch_bounds__(256) void k3_pool(
    const float* __restrict__ w_pool, const float* __restrict__ b_pool,
    const unsigned long long* __restrict__ bits, float* __restrict__ out)
{
    const int tid = threadIdx.x;
    const int c = tid & 31;
    const int g = tid >> 5;
    const int b = blockIdx.x * 8 + g;
    if (b >= B) return;
    float acc = b_pool[c];
    #pragma unroll
    for (int t = 0; t < T; t++) {
        unsigned long long m = bits[(size_t)b * T + t];
        while (m) {
            int j = __builtin_ctzll(m);
            m &= m - 1;
            acc += w_pool[(size_t)(t * H2 + j) * C + c];
        }
    }
    out[(size_t)b * C + c] = acc;
}

extern "C" void kernel_launch(void* const* d_in, const int* in_sizes, int n_in,
                              void* d_out, int out_size, void* d_ws, size_t ws_size,
                              hipStream_t stream)
{
    const float* x      = (const float*)d_in[0];
    const int*   nodes  = (const int*)d_in[1];
    const int*   nbr1   = (const int*)d_in[2];
    const int*   nbr2   = (const int*)d_in[3];
    const float* w_l0   = (const float*)d_in[4];
    const float* b_l0   = (const float*)d_in[5];
    const float* w_r0   = (const float*)d_in[6];
    const float* b_r0   = (const float*)d_in[7];
    const float* w_l1   = (const float*)d_in[8];
    const float* b_l1   = (const float*)d_in[9];
    const float* w_r1   = (const float*)d_in[10];
    const float* b_r1   = (const float*)d_in[11];
    const float* w_pool = (const float*)d_in[12];
    const float* b_pool = (const float*)d_in[13];
    float* out = (float*)d_out;

    const size_t pq_bytes   = (size_t)N_NODES * 256 * sizeof(float);          // 512 MB
    const size_t bits_bytes = (size_t)B * T * sizeof(unsigned long long);     // 1.28 MB
    // whi/wlo (64KB each) overlap the bits region: consumed by k0/k1 before
    // k2 writes bits. Total ws requirement unchanged (pq + bits).

    if (ws_size >= pq_bytes + bits_bytes) {
        float* PQ = (float*)d_ws;
        unsigned short* whi = (unsigned short*)((char*)d_ws + pq_bytes);
        unsigned short* wlo = whi + 256 * 128;
        unsigned long long* bits = (unsigned long long*)((char*)d_ws + pq_bytes);

        k0_wsplit<<<128, 256, 0, stream>>>(w_l0, w_r0, whi, wlo);
        k1_mfma<<<(N_NODES + 63) / 64, 256, 0, stream>>>(x, whi, wlo, b_l0, b_r0, PQ);
        k2_step<0><<<(B * T) / 4, 256, 0, stream>>>(x, nodes, nbr1, nbr2,
            w_l0, b_l0, w_r0, b_r0, w_l1, b_l1, w_r1, b_r1, PQ, bits);
        k3_pool<<<B / 8, 256, 0, stream>>>(w_pool, b_pool, bits, out);
    } else {
        unsigned long long* bits = (unsigned long long*)d_ws;
        k2_step<1><<<(B * T) / 4, 256, 0, stream>>>(x, nodes, nbr1, nbr2,
            w_l0, b_l0, w_r0, b_r0, w_l1, b_l1, w_r1, b_r1, nullptr, bits);
        k3_pool<<<B / 8, 256, 0, stream>>>(w_pool, b_pool, bits, out);
    }
}

// Round 9
// 557.794 us; speedup vs baseline: 1.3870x; 1.0025x over previous
//
#include <hip/hip_runtime.h>
#include <hip/hip_bf16.h>
#include <stdint.h>

#define N_NODES 500000
#define F 128
#define B 20000
#define T 8
#define H1 128
#define H2 64
#define C 32
#define S1 5
#define S2 2

typedef __attribute__((ext_vector_type(8))) short s16x8;
typedef __attribute__((ext_vector_type(4))) float f32x4;
typedef __attribute__((ext_vector_type(2))) float f32x2;

// round-to-nearest-even fp32 -> bf16 (bit-level, deterministic)
__device__ __forceinline__ unsigned short f2bf(float v) {
    unsigned int u = __builtin_bit_cast(unsigned int, v);
    unsigned int r = (u + 0x7fffu + ((u >> 16) & 1u)) >> 16;
    return (unsigned short)r;
}
__device__ __forceinline__ float bf2f(unsigned short u) {
    unsigned int x = ((unsigned int)u) << 16;
    return __builtin_bit_cast(float, x);
}

// ---------------------------------------------------------------------------
// K0: split [w_l0 | w_r0] (128x256 fp32) into bf16 hi/lo, TRANSPOSED to
// [n][k] so MFMA B-fragments (8 contiguous k per lane) are single b128 loads.
// Lives in the d_ws "bits" region (consumed before K2 writes bits).
// ---------------------------------------------------------------------------
__global__ __launch_bounds__(256) void k0_wsplit(
    const float* __restrict__ wl, const float* __restrict__ wr,
    unsigned short* __restrict__ whi, unsigned short* __restrict__ wlo)
{
    int idx = blockIdx.x * 256 + threadIdx.x;     // [n][k], 256*128 total
    if (idx >= 256 * 128) return;
    int n = idx >> 7, k = idx & 127;
    float v = (n < 128) ? wl[(size_t)k * 128 + n] : wr[(size_t)k * 128 + (n - 128)];
    unsigned short h = f2bf(v);
    whi[idx] = h;
    wlo[idx] = f2bf(v - bf2f(h));
}

// ---------------------------------------------------------------------------
// K1: PQ[n] = [ x[n]@w_l0 + b_l0 | x[n]@w_r0 + b_r0 ]  via bf16x3 split-MFMA.
// BM=64 rows/block, 4 waves each owning a 64-col quarter of N=256.
// Whole 64x128 A-slab split into LDS once, ONE barrier, barrier-free MFMA.
// Fragment layouts (m89-verified): A row=l&15, k=8*(l>>4)+j; B (stored
// [n][k]) n=l&15, k=8*(l>>4)+j; D col=l&15, row=4*(l>>4)+j.
// ---------------------------------------------------------------------------
__global__ __launch_bounds__(256) void k1_mfma(
    const float* __restrict__ x,
    const unsigned short* __restrict__ whi,
    const unsigned short* __restrict__ wlo,
    const float* __restrict__ b_l0, const float* __restrict__ b_r0,
    float* __restrict__ PQ)
{
    __shared__ unsigned short Ahi[64][136];   // 128 + 8 pad (rows 272B)
    __shared__ unsigned short Alo[64][136];

    const int tid  = threadIdx.x;
    const int wv   = tid >> 6;               // wave 0..3 -> cols wv*64..+63
    const int lane = tid & 63;
    const int fl   = lane & 15;
    const int fg   = lane >> 4;
    const int m0   = blockIdx.x * 64;

    // ---- split phase: thread (row, 32-col segment) ----
    const int srow = tid >> 2;                // 0..63
    const int sc0  = (tid & 3) * 32;          // 0,32,64,96
    const int rowc = min(m0 + srow, N_NODES - 1);   // clamp for tail block
    const float* xbase = x + (size_t)rowc * F + sc0;

    #pragma unroll
    for (int c = 0; c < 4; ++c) {
        float4 v0 = *(const float4*)(xbase + c * 8);
        float4 v1 = *(const float4*)(xbase + c * 8 + 4);
        float xv[8] = {v0.x, v0.y, v0.z, v0.w, v1.x, v1.y, v1.z, v1.w};
        s16x8 ph, pl;
        #pragma unroll
        for (int j = 0; j < 8; ++j) {
            unsigned short h = f2bf(xv[j]);
            ph[j] = (short)h;
            pl[j] = (short)f2bf(xv[j] - bf2f(h));
        }
        *(s16x8*)&Ahi[srow][sc0 + c * 8] = ph;
        *(s16x8*)&Alo[srow][sc0 + c * 8] = pl;
    }
    __syncthreads();

    // per-nf bias (col = wv*64 + 16*nf + fl, fixed per thread)
    float bias_nf[4];
    #pragma unroll
    for (int nf = 0; nf < 4; ++nf) {
        int cc = wv * 64 + 16 * nf + fl;
        bias_nf[nf] = (cc < 128) ? b_l0[cc] : b_r0[cc - 128];
    }

    f32x4 acc[4][4];
    #pragma unroll
    for (int mf = 0; mf < 4; ++mf)
        #pragma unroll
        for (int nf = 0; nf < 4; ++nf)
            acc[mf][nf] = (f32x4){0.f, 0.f, 0.f, 0.f};

    // ---- barrier-free MFMA phase ----
    #pragma unroll
    for (int ks = 0; ks < 4; ++ks) {
        // B fragments (global, L2-hot 128KB)
        s16x8 bh[4], bl[4];
        #pragma unroll
        for (int nf = 0; nf < 4; ++nf) {
            size_t n = (size_t)(wv * 64 + 16 * nf + fl);
            bh[nf] = *(const s16x8*)(whi + n * 128 + ks * 32 + fg * 8);
            bl[nf] = *(const s16x8*)(wlo + n * 128 + ks * 32 + fg * 8);
        }
        // A fragments (LDS)
        s16x8 ah[4], al[4];
        #pragma unroll
        for (int mf = 0; mf < 4; ++mf) {
            ah[mf] = *(const s16x8*)&Ahi[16 * mf + fl][ks * 32 + fg * 8];
            al[mf] = *(const s16x8*)&Alo[16 * mf + fl][ks * 32 + fg * 8];
        }
        // 3-pass MFMA (HH, HL, LH)
        #pragma unroll
        for (int mf = 0; mf < 4; ++mf)
            #pragma unroll
            for (int nf = 0; nf < 4; ++nf) {
                acc[mf][nf] = __builtin_amdgcn_mfma_f32_16x16x32_bf16(
                    ah[mf], bh[nf], acc[mf][nf], 0, 0, 0);
                acc[mf][nf] = __builtin_amdgcn_mfma_f32_16x16x32_bf16(
                    ah[mf], bl[nf], acc[mf][nf], 0, 0, 0);
                acc[mf][nf] = __builtin_amdgcn_mfma_f32_16x16x32_bf16(
                    al[mf], bh[nf], acc[mf][nf], 0, 0, 0);
            }
    }

    // ---- store: D col=fl (per nf), row = 16*mf + 4*fg + j ----
    #pragma unroll
    for (int mf = 0; mf < 4; ++mf) {
        #pragma unroll
        for (int j = 0; j < 4; ++j) {
            int row = m0 + 16 * mf + 4 * fg + j;
            if (row < N_NODES) {
                #pragma unroll
                for (int nf = 0; nf < 4; ++nf) {
                    int col = wv * 64 + 16 * nf + fl;
                    PQ[(size_t)row * 256 + col] = acc[mf][nf][j] + bias_nf[nf];
                }
            }
        }
    }
}

// ---------------------------------------------------------------------------
// K2: one wave per (b,t). All 21 row-gathers pinned simultaneously live via
// a single empty asm (forces the compiler to issue every global_load before
// the first use -> full memory-level parallelism per wave; R8 lesson:
// VGPR_Count=24 meant the compiler was serializing the gathers in batches).
// ---------------------------------------------------------------------------
__device__ __forceinline__ void mask_walk(unsigned long long m, int par,
                                          const float* __restrict__ w,
                                          int lane, float& acc)
{
    while (m) {
        int i = __builtin_ctzll(m);
        m &= m - 1;
        acc += w[(size_t)(2 * i + par) * H2 + lane];
    }
}

template <int MODE>
__global__ __launch_bounds__(256) void k2_step(
    const float* __restrict__ x,
    const int* __restrict__ nodes, const int* __restrict__ nbr1,
    const int* __restrict__ nbr2,
    const float* __restrict__ w_l0, const float* __restrict__ b_l0,
    const float* __restrict__ w_r0, const float* __restrict__ b_r0,
    const float* __restrict__ w_l1, const float* __restrict__ b_l1,
    const float* __restrict__ w_r1, const float* __restrict__ b_r1,
    const float* __restrict__ PQ,
    unsigned long long* __restrict__ bits)
{
    const int lane = threadIdx.x & 63;
    const int wv   = threadIdx.x >> 6;
    const int gw   = __builtin_amdgcn_readfirstlane((int)(blockIdx.x * 4 + wv));
    const int b    = gw >> 3;
    const int t    = gw & 7;
    const int c2   = lane * 2;

    if (MODE == 0) {
        const int i_self = nodes[b];
        int i1[S1];
        #pragma unroll
        for (int s = 0; s < S1; s++) i1[s] = nbr1[t * (B * S1) + b * S1 + s];
        int i2[S1 * S2];
        #pragma unroll
        for (int q = 0; q < S1 * S2; q++) i2[q] = nbr2[t * (B * S1 * S2) + b * S1 * S2 + q];

        // ---- issue all 21 gathers; pin them simultaneously live ----
        f32x2 sp = *(const f32x2*)(PQ + (size_t)i_self * 256 + c2);
        f32x2 p1[S1], q1[S1], q2[S1 * S2];
        #pragma unroll
        for (int s = 0; s < S1; s++)
            p1[s] = *(const f32x2*)(PQ + (size_t)i1[s] * 256 + c2);
        #pragma unroll
        for (int s = 0; s < S1; s++)
            q1[s] = *(const f32x2*)(PQ + (size_t)i1[s] * 256 + 128 + c2);
        #pragma unroll
        for (int u = 0; u < S1 * S2; u++)
            q2[u] = *(const f32x2*)(PQ + (size_t)i2[u] * 256 + 128 + c2);

        asm volatile(""
            : "+v"(sp),
              "+v"(p1[0]), "+v"(p1[1]), "+v"(p1[2]), "+v"(p1[3]), "+v"(p1[4]),
              "+v"(q1[0]), "+v"(q1[1]), "+v"(q1[2]), "+v"(q1[3]), "+v"(q1[4]),
              "+v"(q2[0]), "+v"(q2[1]), "+v"(q2[2]), "+v"(q2[3]), "+v"(q2[4]),
              "+v"(q2[5]), "+v"(q2[6]), "+v"(q2[7]), "+v"(q2[8]), "+v"(q2[9]));

        // ---- ballots ----
        float qsx = 0.f, qsy = 0.f;
        #pragma unroll
        for (int s = 0; s < S1; s++) { qsx += q1[s].x; qsy += q1[s].y; }
        unsigned long long mLx = __ballot(sp.x + 0.2f * qsx >= 1.0f);
        unsigned long long mLy = __ballot(sp.y + 0.2f * qsy >= 1.0f);
        unsigned long long mRx[S1], mRy[S1];
        #pragma unroll
        for (int r = 0; r < S1; r++) {
            float cx = p1[r].x + 0.5f * (q2[2 * r].x + q2[2 * r + 1].x);
            float cy = p1[r].y + 0.5f * (q2[2 * r].y + q2[2 * r + 1].y);
            mRx[r] = __ballot(cx >= 1.0f);
            mRy[r] = __ballot(cy >= 1.0f);
        }

        // ---- sparse layer-1 accumulation, independent chains ----
        float aL0 = 0.f, aL1 = 0.f;
        float aR0 = 0.f, aR1 = 0.f, aR2 = 0.f, aR3 = 0.f;
        mask_walk(mLx, 0, w_l1, lane, aL0);
        mask_walk(mLy, 1, w_l1, lane, aL1);
        mask_walk(mRx[0], 0, w_r1, lane, aR0);
        mask_walk(mRy[0], 1, w_r1, lane, aR1);
        mask_walk(mRx[1], 0, w_r1, lane, aR2);
        mask_walk(mRy[1], 1, w_r1, lane, aR3);
        mask_walk(mRx[2], 0, w_r1, lane, aR0);
        mask_walk(mRy[2], 1, w_r1, lane, aR1);
        mask_walk(mRx[3], 0, w_r1, lane, aR2);
        mask_walk(mRy[3], 1, w_r1, lane, aR3);
        mask_walk(mRx[4], 0, w_r1, lane, aR0);
        mask_walk(mRy[4], 1, w_r1, lane, aR1);

        float cur1 = (aL0 + aL1) + 0.2f * ((aR0 + aR1) + (aR2 + aR3))
                   + b_l1[lane] + b_r1[lane];
        unsigned long long sb = __ballot(cur1 >= 1.0f);
        if (lane == 0) bits[(size_t)b * T + t] = sb;
    } else {
        __shared__ float a_lds[4][F];
        __shared__ float n_lds[4][F];
        const int i_self = nodes[b];
        int i1[S1];
        #pragma unroll
        for (int s = 0; s < S1; s++) i1[s] = nbr1[t * (B * S1) + b * S1 + s];
        int i2[S1 * S2];
        #pragma unroll
        for (int q = 0; q < S1 * S2; q++) i2[q] = nbr2[t * (B * S1 * S2) + b * S1 * S2 + q];

        float accL = 0.f, accR = 0.f;
        const float b0x = b_l0[c2] + b_r0[c2];
        const float b0y = b_l0[c2 + 1] + b_r0[c2 + 1];
        float nsx = 0.f, nsy = 0.f;
        #pragma unroll 1
        for (int r = 1; r < 6; r++) {
            const float* ar = x + (size_t)i1[r - 1] * F;
            float ax = ar[c2], ay = ar[c2 + 1];
            nsx += ax; nsy += ay;
            const float* ch0 = x + (size_t)i2[(r - 1) * 2] * F;
            const float* ch1 = x + (size_t)i2[(r - 1) * 2 + 1] * F;
            float nx = 0.5f * (ch0[c2]     + ch1[c2]);
            float ny = 0.5f * (ch0[c2 + 1] + ch1[c2 + 1]);
            a_lds[wv][c2] = ax; a_lds[wv][c2 + 1] = ay;
            n_lds[wv][c2] = nx; n_lds[wv][c2 + 1] = ny;
            float cx = b0x, cy = b0y;
            #pragma unroll 4
            for (int k = 0; k < F; k++) {
                float ak = a_lds[wv][k], nk = n_lds[wv][k];
                const float* wl = w_l0 + (size_t)k * H1 + c2;
                const float* wr = w_r0 + (size_t)k * H1 + c2;
                cx += ak * wl[0] + nk * wr[0];
                cy += ak * wl[1] + nk * wr[1];
            }
            mask_walk(__ballot(cx >= 1.0f), 0, w_r1, lane, accR);
            mask_walk(__ballot(cy >= 1.0f), 1, w_r1, lane, accR);
        }
        {
            const float* ar = x + (size_t)i_self * F;
            float ax = ar[c2], ay = ar[c2 + 1];
            a_lds[wv][c2] = ax; a_lds[wv][c2 + 1] = ay;
            n_lds[wv][c2] = 0.2f * nsx; n_lds[wv][c2 + 1] = 0.2f * nsy;
            float cx = b0x, cy = b0y;
            #pragma unroll 4
            for (int k = 0; k < F; k++) {
                float ak = a_lds[wv][k], nk = n_lds[wv][k];
                const float* wl = w_l0 + (size_t)k * H1 + c2;
                const float* wr = w_r0 + (size_t)k * H1 + c2;
                cx += ak * wl[0] + nk * wr[0];
                cy += ak * wl[1] + nk * wr[1];
            }
            mask_walk(__ballot(cx >= 1.0f), 0, w_l1, lane, accL);
            mask_walk(__ballot(cy >= 1.0f), 1, w_l1, lane, accL);
        }
        float cur1 = accL + 0.2f * accR + b_l1[lane] + b_r1[lane];
        unsigned long long sb = __ballot(cur1 >= 1.0f);
        if (lane == 0) bits[(size_t)b * T + t] = sb;
    }
}

// ---------------------------------------------------------------------------
// K3: out[b][c] = b_pool[c] + sum over set spike bits of w_pool[(t*64+j)][c]
// ---------------------------------------------------------------------------
__global__ __launch_bounds__(256) void k3_pool(
    const float* __restrict__ w_pool, const float* __restrict__ b_pool,
    const unsigned long long* __restrict__ bits, float* __restrict__ out)
{
    const int tid = threadIdx.x;
    const int c = tid & 31;
    const int g = tid >> 5;
    const int b = blockIdx.x * 8 + g;
    if (b >= B) return;
    float acc = b_pool[c];
    #pragma unroll
    for (int t = 0; t < T; t++) {
        unsigned long long m = bits[(size_t)b * T + t];
        while (m) {
            int j = __builtin_ctzll(m);
            m &= m - 1;
            acc += w_pool[(size_t)(t * H2 + j) * C + c];
        }
    }
    out[(size_t)b * C + c] = acc;
}

extern "C" void kernel_launch(void* const* d_in, const int* in_sizes, int n_in,
                              void* d_out, int out_size, void* d_ws, size_t ws_size,
                              hipStream_t stream)
{
    const float* x      = (const float*)d_in[0];
    const int*   nodes  = (const int*)d_in[1];
    const int*   nbr1   = (const int*)d_in[2];
    const int*   nbr2   = (const int*)d_in[3];
    const float* w_l0   = (const float*)d_in[4];
    const float* b_l0   = (const float*)d_in[5];
    const float* w_r0   = (const float*)d_in[6];
    const float* b_r0   = (const float*)d_in[7];
    const float* w_l1   = (const float*)d_in[8];
    const float* b_l1   = (const float*)d_in[9];
    const float* w_r1   = (const float*)d_in[10];
    const float* b_r1   = (const float*)d_in[11];
    const float* w_pool = (const float*)d_in[12];
    const float* b_pool = (const float*)d_in[13];
    float* out = (float*)d_out;

    const size_t pq_bytes   = (size_t)N_NODES * 256 * sizeof(float);          // 512 MB
    const size_t bits_bytes = (size_t)B * T * sizeof(unsigned long long);     // 1.28 MB
    // whi/wlo (64KB each) overlap the bits region: consumed by k0/k1 before
    // k2 writes bits. Total ws requirement unchanged (pq + bits).

    if (ws_size >= pq_bytes + bits_bytes) {
        float* PQ = (float*)d_ws;
        unsigned short* whi = (unsigned short*)((char*)d_ws + pq_bytes);
        unsigned short* wlo = whi + 256 * 128;
        unsigned long long* bits = (unsigned long long*)((char*)d_ws + pq_bytes);

        k0_wsplit<<<128, 256, 0, stream>>>(w_l0, w_r0, whi, wlo);
        k1_mfma<<<(N_NODES + 63) / 64, 256, 0, stream>>>(x, whi, wlo, b_l0, b_r0, PQ);
        k2_step<0><<<(B * T) / 4, 256, 0, stream>>>(x, nodes, nbr1, nbr2,
            w_l0, b_l0, w_r0, b_r0, w_l1, b_l1, w_r1, b_r1, PQ, bits);
        k3_pool<<<B / 8, 256, 0, stream>>>(w_pool, b_pool, bits, out);
    } else {
        unsigned long long* bits = (unsigned long long*)d_ws;
        k2_step<1><<<(B * T) / 4, 256, 0, stream>>>(x, nodes, nbr1, nbr2,
            w_l0, b_l0, w_r0, b_r0, w_l1, b_l1, w_r1, b_r1, nullptr, bits);
        k3_pool<<<B / 8, 256, 0, stream>>>(w_pool, b_pool, bits, out);
    }
}